// Round 3
// baseline (61.300 us; speedup 1.0000x reference)
//
#include <hip/hip_runtime.h>
#include <stdint.h>

// IDs in [0, 100000): 100000 bits -> 3125 u32 words; pad slices to 3136 words
// (multiple of 64) so every bitset slice is 16B-aligned for uint4 ops.
#define NWORDS 3125
#define NWP    3136
#define NVEC   (NWP / 4)             // 784 uint4 per bitset
#define SCAN_BLOCKS 1024
#define SCAN_THREADS 512
#define NCHUNK 32                    // partial bitsets produced by reduce
#define CHUNK  (SCAN_BLOCKS / NCHUNK) // 32 copies OR'd per reduce thread

__global__ void zero_ws_kernel(uint32_t* __restrict__ w, int n) {
    int i = blockIdx.x * blockDim.x + threadIdx.x;
    if (i < n) w[i] = 0u;
}

__global__ void build_hr_kernel(const int* __restrict__ neg, int B,
                                uint32_t* __restrict__ headb,
                                uint32_t* __restrict__ relb) {
    int b = blockIdx.x * blockDim.x + threadIdx.x;
    if (b >= B) return;
    int h = neg[b * 3 + 0];
    int r = neg[b * 3 + 1];
    atomicOr(&headb[h >> 5], 1u << (h & 31));
    atomicOr(&relb[r >> 5], 1u << (r & 31));
}

// Process one group of 4 triples held in three int4s.
#define PROC(A, B_, C_) do {                                                   \
    int hs[4] = {(A).x, (A).w, (B_).z, (C_).y};                                \
    int rs[4] = {(A).y, (B_).x, (B_).w, (C_).z};                               \
    int ts[4] = {(A).z, (B_).y, (C_).x, (C_).w};                               \
    _Pragma("unroll")                                                          \
    for (int k = 0; k < 4; ++k) {                                              \
        uint32_t hbit = (sh[hs[k] >> 5] >> (hs[k] & 31)) & 1u;                 \
        uint32_t rbit = (sr[rs[k] >> 5] >> (rs[k] & 31)) & 1u;                 \
        if (hbit & rbit) {                                                     \
            int t = ts[k];                                                     \
            uint32_t bit = 1u << (t & 31);                                     \
            if (!(st[t >> 5] & bit)) atomicOr(&st[t >> 5], bit);               \
        }                                                                      \
    }                                                                          \
} while (0)

// Stream mapped_triples; mark surviving tails in a per-block LDS bitset;
// write the private bitset to its ws slice with plain vector stores.
__global__ __launch_bounds__(SCAN_THREADS, 8) void scan_triples_kernel(
        const int* __restrict__ mt, int N,
        const uint32_t* __restrict__ headb,
        const uint32_t* __restrict__ relb,
        uint32_t* __restrict__ copies) {
    __shared__ __align__(16) uint32_t sh[NWP];
    __shared__ __align__(16) uint32_t sr[NWP];
    __shared__ __align__(16) uint32_t st[NWP];

    uint4* sh4 = (uint4*)sh;
    uint4* sr4 = (uint4*)sr;
    uint4* st4 = (uint4*)st;
    const uint4* hb4 = (const uint4*)headb;
    const uint4* rb4 = (const uint4*)relb;
    for (int i = threadIdx.x; i < NVEC; i += blockDim.x) {
        sh4[i] = hb4[i];
        sr4[i] = rb4[i];
        st4[i] = make_uint4(0u, 0u, 0u, 0u);
    }
    __syncthreads();

    const int tid = blockIdx.x * blockDim.x + threadIdx.x;
    const int stride = gridDim.x * blockDim.x;
    const int ngroups = N >> 2;  // 4 triples = 12 ints = 3 x int4
    const int4* __restrict__ mt4 = (const int4*)mt;

    int g = tid;
    // 2-deep unroll: 6 int4 loads (96 B/lane) in flight before LDS processing
    for (; g + stride < ngroups; g += 2 * stride) {
        size_t b0 = (size_t)g * 3;
        size_t b1 = (size_t)(g + stride) * 3;
        int4 a0 = mt4[b0 + 0], a1 = mt4[b0 + 1], a2 = mt4[b0 + 2];
        int4 d0 = mt4[b1 + 0], d1 = mt4[b1 + 1], d2 = mt4[b1 + 2];
        PROC(a0, a1, a2);
        PROC(d0, d1, d2);
    }
    for (; g < ngroups; g += stride) {
        size_t b0 = (size_t)g * 3;
        int4 a0 = mt4[b0 + 0], a1 = mt4[b0 + 1], a2 = mt4[b0 + 2];
        PROC(a0, a1, a2);
    }
    // scalar remainder (N not divisible by 4)
    int base = ngroups << 2;
    for (int i = base + tid; i < N; i += stride) {
        int h = mt[i * 3 + 0], r = mt[i * 3 + 1], t = mt[i * 3 + 2];
        if (((sh[h >> 5] >> (h & 31)) & 1u) && ((sr[r >> 5] >> (r & 31)) & 1u)) {
            uint32_t bit = 1u << (t & 31);
            if (!(st[t >> 5] & bit)) atomicOr(&st[t >> 5], bit);
        }
    }

    __syncthreads();
    uint4* dst4 = (uint4*)(copies + (size_t)blockIdx.x * NWP);
    for (int i = threadIdx.x; i < NVEC; i += blockDim.x) dst4[i] = st4[i];
}

// OR-reduce SCAN_BLOCKS copies into NCHUNK partial bitsets (plain stores).
__global__ void reduce_tails_kernel(const uint32_t* __restrict__ copies,
                                    uint32_t* __restrict__ partials) {
    int idx = blockIdx.x * blockDim.x + threadIdx.x;
    if (idx >= NCHUNK * NVEC) return;
    int i  = idx % NVEC;            // uint4 index (consecutive threads -> coalesced)
    int ch = idx / NVEC;            // which partial
    const uint4* c4 = (const uint4*)copies;
    uint4 acc = make_uint4(0u, 0u, 0u, 0u);
    int c0 = ch * CHUNK;
    for (int c = 0; c < CHUNK; ++c) {
        uint4 v = c4[(size_t)(c0 + c) * NVEC + i];
        acc.x |= v.x; acc.y |= v.y; acc.z |= v.z; acc.w |= v.w;
    }
    ((uint4*)partials)[(size_t)ch * NVEC + i] = acc;
}

__global__ void finalize_kernel(const int* __restrict__ neg, int B,
                                const uint32_t* __restrict__ partials,
                                int* __restrict__ out) {
    int b = blockIdx.x * blockDim.x + threadIdx.x;
    if (b >= B) return;
    int h = neg[b * 3 + 0];
    int r = neg[b * 3 + 1];
    int t = neg[b * 3 + 2];
    int w = t >> 5;
    uint32_t acc = 0u;
#pragma unroll
    for (int c = 0; c < NCHUNK; ++c) acc |= partials[(size_t)c * NWP + w];
    bool filtered = (acc >> (t & 31)) & 1u;
    int keep = filtered ? 0 : 1;
    out[b * 3 + 0] = keep ? h : -1;
    out[b * 3 + 1] = keep ? r : -1;
    out[b * 3 + 2] = keep ? t : -1;
    out[3 * B + b] = keep;  // keep_mask as 0/1 int32
}

extern "C" void kernel_launch(void* const* d_in, const int* in_sizes, int n_in,
                              void* d_out, int out_size, void* d_ws, size_t ws_size,
                              hipStream_t stream) {
    const int* neg = (const int*)d_in[0];   // [B,3] int32
    const int* mt  = (const int*)d_in[1];   // [N,3] int32
    int B = in_sizes[0] / 3;
    int N = in_sizes[1] / 3;
    int* out = (int*)d_out;

    uint32_t* ws       = (uint32_t*)d_ws;
    uint32_t* headb    = ws;                       // NWP words
    uint32_t* relb     = ws + NWP;                 // NWP words
    uint32_t* partials = ws + 2 * NWP;             // NCHUNK * NWP words
    uint32_t* copies   = ws + (2 + NCHUNK) * NWP;  // SCAN_BLOCKS * NWP words (~12.8 MB)

    // 1) zero head/rel bitsets (ws is NOT re-poisoned between replays;
    //    copies/partials are fully overwritten every call)
    zero_ws_kernel<<<(2 * NWP + 255) / 256, 256, 0, stream>>>(ws, 2 * NWP);
    // 2) build head/rel presence bitsets
    build_hr_kernel<<<(B + 255) / 256, 256, 0, stream>>>(neg, B, headb, relb);
    // 3) stream triples, mark surviving tails into per-block private bitsets
    scan_triples_kernel<<<SCAN_BLOCKS, SCAN_THREADS, 0, stream>>>(
        mt, N, headb, relb, copies);
    // 4) OR-reduce copies into NCHUNK partial bitsets (no atomics)
    {
        int total = NCHUNK * NVEC;
        reduce_tails_kernel<<<(total + 255) / 256, 256, 0, stream>>>(copies, partials);
    }
    // 5) final OR over partials + emit filtered batch + keep mask
    finalize_kernel<<<(B + 255) / 256, 256, 0, stream>>>(neg, B, partials, out);
}

// Round 4
// 57.196 us; speedup vs baseline: 1.0718x; 1.0718x over previous
//
#include <hip/hip_runtime.h>
#include <stdint.h>

// IDs in [0, 100000): 100000 bits -> 3125 u32 words; pad to 3136 (x64) so
// every bitset slice is 16B-aligned for uint4 ops.
#define NWORDS 3125
#define NWP    3136
#define NVEC   (NWP / 4)              // 784 uint4 per bitset
#define SCAN_BLOCKS 1024
#define SCAN_THREADS 512
#define NCHUNK 32                     // stage-A partial bitsets
#define CHUNK  (SCAN_BLOCKS / NCHUNK) // 32 copies OR'd per stage-A thread

// int4 with alignment relaxed to 4B: gfx950 supports dword-aligned dwordx4
// (unaligned-access-mode); keeps the vector load at 12B offsets.
typedef int4 __attribute__((aligned(4))) int4_a4;

__global__ void build_hr_kernel(const int* __restrict__ neg, int B,
                                uint32_t* __restrict__ headb,
                                uint32_t* __restrict__ relb) {
    int b = blockIdx.x * blockDim.x + threadIdx.x;
    if (b >= B) return;
    int h = neg[b * 3 + 0];
    int r = neg[b * 3 + 1];
    atomicOr(&headb[h >> 5], 1u << (h & 31));
    atomicOr(&relb[r >> 5], 1u << (r & 31));
}

// Stream mapped_triples with one overlapping 16B load per triple (12B stride):
// h,r,t arrive in .x,.y,.z — no repacking, ~minimal line-request rate.
// Surviving tails marked in a per-block LDS bitset, then stored (no atomics).
__global__ __launch_bounds__(SCAN_THREADS, 8) void scan_triples_kernel(
        const int* __restrict__ mt, int N,
        const uint32_t* __restrict__ headb,
        const uint32_t* __restrict__ relb,
        uint32_t* __restrict__ copies) {
    __shared__ __align__(16) uint32_t sh[NWP];
    __shared__ __align__(16) uint32_t sr[NWP];
    __shared__ __align__(16) uint32_t st[NWP];

    uint4* sh4 = (uint4*)sh;
    uint4* sr4 = (uint4*)sr;
    uint4* st4 = (uint4*)st;
    const uint4* hb4 = (const uint4*)headb;
    const uint4* rb4 = (const uint4*)relb;
    for (int i = threadIdx.x; i < NVEC; i += blockDim.x) {
        sh4[i] = hb4[i];
        sr4[i] = rb4[i];
        st4[i] = make_uint4(0u, 0u, 0u, 0u);
    }
    __syncthreads();

    const uint32_t tid = blockIdx.x * blockDim.x + threadIdx.x;
    const uint32_t stride = gridDim.x * blockDim.x;
    const char* __restrict__ base = (const char*)mt;

    // all but the last triple: overlapping int4 loads (reads 4B past triple;
    // in-bounds because triple i+1 exists). 32-bit byte offsets (<2^31).
    for (uint32_t i = tid; i < (uint32_t)(N - 1); i += stride) {
        int4 v = *(const int4_a4*)(base + i * 12u);
        int h = v.x, r = v.y, t = v.z;
        uint32_t hbit = (sh[h >> 5] >> (h & 31)) & 1u;
        uint32_t rbit = (sr[r >> 5] >> (r & 31)) & 1u;
        if (hbit & rbit) {
            uint32_t bit = 1u << (t & 31);
            if (!(st[t >> 5] & bit)) atomicOr(&st[t >> 5], bit);
        }
    }
    // last triple: scalar loads (no over-read past the buffer end)
    if (tid == 0) {
        int h = mt[(size_t)(N - 1) * 3 + 0];
        int r = mt[(size_t)(N - 1) * 3 + 1];
        int t = mt[(size_t)(N - 1) * 3 + 2];
        if (((sh[h >> 5] >> (h & 31)) & 1u) && ((sr[r >> 5] >> (r & 31)) & 1u))
            atomicOr(&st[t >> 5], 1u << (t & 31));
    }

    __syncthreads();
    uint4* dst4 = (uint4*)(copies + (size_t)blockIdx.x * NWP);
    for (int i = threadIdx.x; i < NVEC; i += blockDim.x) dst4[i] = st4[i];
}

// Stage A: OR-reduce SCAN_BLOCKS copies into NCHUNK partials (plain stores).
__global__ void reduceA_kernel(const uint32_t* __restrict__ copies,
                               uint32_t* __restrict__ partials) {
    int idx = blockIdx.x * blockDim.x + threadIdx.x;
    if (idx >= NCHUNK * NVEC) return;
    int i  = idx % NVEC;
    int ch = idx / NVEC;
    const uint4* c4 = (const uint4*)copies;
    uint4 acc = make_uint4(0u, 0u, 0u, 0u);
    int c0 = ch * CHUNK;
    for (int c = 0; c < CHUNK; ++c) {
        uint4 v = c4[(size_t)(c0 + c) * NVEC + i];
        acc.x |= v.x; acc.y |= v.y; acc.z |= v.z; acc.w |= v.w;
    }
    ((uint4*)partials)[(size_t)ch * NVEC + i] = acc;
}

// Stage B: OR the NCHUNK partials into one final tail bitset.
__global__ void reduceB_kernel(const uint32_t* __restrict__ partials,
                               uint32_t* __restrict__ final_b) {
    int w = blockIdx.x * blockDim.x + threadIdx.x;
    if (w >= NWP) return;
    uint32_t acc = 0u;
#pragma unroll
    for (int c = 0; c < NCHUNK; ++c) acc |= partials[c * NWP + w];
    final_b[w] = acc;
}

__global__ void finalize_kernel(const int* __restrict__ neg, int B,
                                const uint32_t* __restrict__ final_b,
                                int* __restrict__ out) {
    int b = blockIdx.x * blockDim.x + threadIdx.x;
    if (b >= B) return;
    int h = neg[b * 3 + 0];
    int r = neg[b * 3 + 1];
    int t = neg[b * 3 + 2];
    bool filtered = (final_b[t >> 5] >> (t & 31)) & 1u;
    int keep = filtered ? 0 : 1;
    out[b * 3 + 0] = keep ? h : -1;
    out[b * 3 + 1] = keep ? r : -1;
    out[b * 3 + 2] = keep ? t : -1;
    out[3 * B + b] = keep;  // keep_mask as 0/1 int32
}

extern "C" void kernel_launch(void* const* d_in, const int* in_sizes, int n_in,
                              void* d_out, int out_size, void* d_ws, size_t ws_size,
                              hipStream_t stream) {
    const int* neg = (const int*)d_in[0];   // [B,3] int32
    const int* mt  = (const int*)d_in[1];   // [N,3] int32
    int B = in_sizes[0] / 3;
    int N = in_sizes[1] / 3;
    int* out = (int*)d_out;

    uint32_t* ws       = (uint32_t*)d_ws;
    uint32_t* headb    = ws;                       // NWP
    uint32_t* relb     = ws + NWP;                 // NWP
    uint32_t* final_b  = ws + 2 * NWP;             // NWP
    uint32_t* partials = ws + 3 * NWP;             // NCHUNK * NWP
    uint32_t* copies   = ws + (3 + NCHUNK) * NWP;  // SCAN_BLOCKS * NWP (~12.8 MB)

    // zero head/rel bitsets (ws not re-poisoned between replays; copies/
    // partials/final are fully overwritten every call)
    hipMemsetAsync(ws, 0, 2 * NWP * sizeof(uint32_t), stream);
    build_hr_kernel<<<(B + 255) / 256, 256, 0, stream>>>(neg, B, headb, relb);
    scan_triples_kernel<<<SCAN_BLOCKS, SCAN_THREADS, 0, stream>>>(
        mt, N, headb, relb, copies);
    {
        int total = NCHUNK * NVEC;
        reduceA_kernel<<<(total + 255) / 256, 256, 0, stream>>>(copies, partials);
    }
    reduceB_kernel<<<(NWP + 255) / 256, 256, 0, stream>>>(partials, final_b);
    finalize_kernel<<<(B + 255) / 256, 256, 0, stream>>>(neg, B, final_b, out);
}